// Round 9
// baseline (122.501 us; speedup 1.0000x reference)
//
#include <hip/hip_runtime.h>

typedef _Float16 f16x8 __attribute__((ext_vector_type(8)));
typedef float f32x4 __attribute__((ext_vector_type(4)));

#define NP 8192
#define KMAX 32
#define CCAP 64            // candidate cap per query (E[c]~10; P(>64) ~ 0)
#define QPB 8              // queries per block
#define LK 0.01f
#define EPSBN 1e-5f
#define NBANK 16

static constexpr int O_OUT = NP * 64;          // 524288
static constexpr int O_POS = O_OUT + NP * 3;   // 548864
static constexpr int O_BAT = O_POS + NP;       // 557056
static constexpr int O_RFL = O_BAT + NP;       // 565248
static constexpr int O_TOT = O_RFL + 4;        // 565252

// ws offsets (in 4-byte elements)
#define F_ECNT  0                       // 1 int
#define F_BST   8                       // 5 ints (segment bounds)
#define F_SUMS  16                      // 16 x 64 floats
#define F_SUMSQ 1040                    // 16 x 64 floats
#define F_ZEND  2064                    // end of zeroed region
#define F_VSEL  4096                    // NP*64 (gamma-sign-selected max/min)

// ---------------- K0: zero stats + is64 detect + segment binary search
__global__ __launch_bounds__(256) void k0_setup(const int* __restrict__ braw,
                                                int* __restrict__ wsi) {
    int t = threadIdx.x;
    for (int i = t; i < F_ZEND; i += 256) wsi[i] = 0;
    __syncthreads();
    // int64 LE viewed as int32 => index NP-1 is a hi-word (0); int32 sorted => 3.
    const int is64 = (braw[NP - 1] == 0) ? 1 : 0;
    if (t < 3) {               // lower_bound(batch >= b), b = 1..3
        int b = t + 1, lo = 0, hi = NP;
        while (lo < hi) {
            int mid = (lo + hi) >> 1;
            int v = is64 ? braw[2 * mid] : braw[mid];
            if (v < b) lo = mid + 1; else hi = mid;
        }
        wsi[F_BST + 1 + t] = lo;
    }
    if (t == 3) wsi[F_BST] = 0;
    if (t == 4) wsi[F_BST + 4] = NP;
}

// ---------------- K1: fused radius search (register scan) + MLP w/ MFMA layer 2
// 1024 blocks x 256 thr; 8 queries/block; wave w owns queries 2w, 2w+1.
__global__ __launch_bounds__(256) __attribute__((amdgpu_waves_per_eu(4, 4)))
void k1_fused(const float* __restrict__ xin,
              const float* __restrict__ pos,
              const float* __restrict__ rfl,
              const float* __restrict__ sf,
              const float* __restrict__ w1,
              const float* __restrict__ b1,
              const float* __restrict__ w2,
              const float* __restrict__ b2,
              const float* __restrict__ gamma,
              float* __restrict__ wsf) {
    __shared__ int cidx[QPB][CCAP];                      // 2 KB
    __shared__ float cd2[QPB][CCAP];                     // 2 KB
    __shared__ __align__(16) float featw[4][16][8];      // 2 KB feature tiles
    __shared__ __align__(16) _Float16 h1s[4][16][72];    // 9 KB, 72-half row pad:
                                                         // conflict-free b128 reads
    __shared__ float sums_s[64], sumsq_s[64];
    __shared__ int lcnt[QPB];
    __shared__ int bst_s[5];
    __shared__ float4 qp4[QPB];                          // (pix,piy,piz, 1/sf[b])
    __shared__ float rfl_q[QPB];
    constexpr float R2C = (float)((0.02 * 2.1) * (0.02 * 2.1));

    int t = threadIdx.x;
    int lane = t & 63;
    int w = t >> 6;
    const int col = lane & 15;     // MFMA: D-col=channel, A-row=edge
    const int quad = lane >> 4;
    int i0 = blockIdx.x * QPB;

    int* ecnt = (int*)wsf;
    float* sums = wsf + F_SUMS;
    float* sumsq = wsf + F_SUMSQ;
    float* vsel = wsf + F_VSEL;

    if (t < 5) bst_s[t] = ((const int*)wsf)[F_BST + t];
    if (t < QPB) lcnt[t] = 0;
    if (t < 64) { sums_s[t] = 0.f; sumsq_s[t] = 0.f; }

    // ---- layer-1 weights (lane = channel) + layer-2 B-fragments (f16 MFMA)
    float w1c[8];
#pragma unroll
    for (int f = 0; f < 8; f++) w1c[f] = w1[f * 64 + lane];
    float b1c = b1[lane];
    // B[k][n]: n = lane&15, k = quad*8 + j (+32 for hi half); 4 channel tiles
    f16x8 b2f[4][2];
#pragma unroll
    for (int tt = 0; tt < 4; tt++)
#pragma unroll
        for (int h = 0; h < 2; h++) {
            f16x8 v;
#pragma unroll
            for (int j = 0; j < 8; j++) {
                int kk = quad * 8 + j + 32 * h;
                v[j] = (_Float16)w2[kk * 64 + 16 * tt + col];
            }
            b2f[tt][h] = v;
        }
    float b2t[4], gamt[4];
#pragma unroll
    for (int tt = 0; tt < 4; tt++) {
        b2t[tt] = b2[16 * tt + col];
        gamt[tt] = gamma[16 * tt + col];
    }
    __syncthreads();

    if (t < QPB) {
        int i = i0 + t;
        int b = (i >= bst_s[1]) + (i >= bst_s[2]) + (i >= bst_s[3]);
        qp4[t] = make_float4(pos[3 * i], pos[3 * i + 1], pos[3 * i + 2], 1.0f / sf[b]);
        rfl_q[t] = rfl[i];
    }
    __syncthreads();

    // ---- all 8 queries in registers
    float qx[QPB], qy[QPB], qz[QPB], qs[QPB];
    int ql[QPB], qh[QPB];
#pragma unroll
    for (int q = 0; q < QPB; q++) {
        float4 p = qp4[q];
        qx[q] = p.x; qy[q] = p.y; qz[q] = p.z;
        qs[q] = p.x * p.x + p.y * p.y + p.z * p.z;
        int i = i0 + q;
        int b = (i >= bst_s[1]) + (i >= bst_s[2]) + (i >= bst_s[3]);
        ql[q] = bst_s[b]; qh[q] = bst_s[b + 1];
    }
    const int lob = ql[0], hib = qh[QPB - 1];   // sorted batches

    // ---- phase 1: candidate-split scan, registers only (R8, proven)
    {
        int k = lob + t;
        float cx = 0.f, cy = 0.f, cz = 0.f;
        if (k < hib) { cx = pos[3 * k]; cy = pos[3 * k + 1]; cz = pos[3 * k + 2]; }
        while (k < hib) {
            int kn = k + 256;
            float nx = cx, ny = cy, nz = cz;
            if (kn < hib) { nx = pos[3 * kn]; ny = pos[3 * kn + 1]; nz = pos[3 * kn + 2]; }
            float sj = cx * cx + cy * cy + cz * cz;
#pragma unroll
            for (int q = 0; q < QPB; q++) {
                if (k >= ql[q] && k < qh[q]) {
                    float d2 = fmaf(-2.0f, qx[q] * cx + qy[q] * cy + qz[q] * cz, qs[q] + sj);
                    if (d2 < R2C) {
                        int p = atomicAdd(&lcnt[q], 1);
                        if (p < CCAP) { cidx[q][p] = k; cd2[q][p] = d2; }
                    }
                }
            }
            cx = nx; cy = ny; cz = nz; k = kn;
        }
    }
    __syncthreads();
    if (t < QPB) {             // rare overflow: exact nearest-KMAX selection
        int c = lcnt[t]; c = c > CCAP ? CCAP : c;
        if (c > KMAX) {
            for (int s = 0; s < KMAX; s++) {
                int bi = s; float bd = cd2[t][s];
                for (int r = s + 1; r < c; r++)
                    if (cd2[t][r] < bd) { bd = cd2[t][r]; bi = r; }
                float tf = cd2[t][s]; cd2[t][s] = cd2[t][bi]; cd2[t][bi] = tf;
                int ti = cidx[t][s]; cidx[t][s] = cidx[t][bi]; cidx[t][bi] = ti;
            }
            c = KMAX;
        }
        lcnt[t] = c;
    }
    __syncthreads();

    // ---- phase 2: per query, 16-edge subtiles; layer 1 VALU, layer 2 MFMA
    float ssum4[4] = {0.f, 0.f, 0.f, 0.f}, ssq4[4] = {0.f, 0.f, 0.f, 0.f};
    const f32x4 zacc = {0.f, 0.f, 0.f, 0.f};
#pragma unroll 1
    for (int qq = 0; qq < 2; qq++) {
        int q = 2 * w + qq;
        int i = i0 + q;
        int c = lcnt[q];
        float4 qv = qp4[q];
        float riq = rfl_q[q];
        float vmx[4], vmn[4];
#pragma unroll
        for (int tt = 0; tt < 4; tt++) { vmx[tt] = -3.4e38f; vmn[tt] = 3.4e38f; }
#pragma unroll 1
        for (int tb = 0; tb < c; tb += 16) {
            int n_e = min(16, c - tb);
            if (lane < n_e) {          // cooperative feature build, lane = edge
                int j = cidx[q][tb + lane];
                float rs = qv.w;
                float4 x4 = ((const float4*)xin)[j];
                float4 fb;
                fb.x = (pos[3 * j + 0] - qv.x) * rs;
                fb.y = (pos[3 * j + 1] - qv.y) * rs;
                fb.z = (pos[3 * j + 2] - qv.z) * rs;
                fb.w = rfl[j] - riq;
                ((float4*)featw[w][lane])[0] = x4;
                ((float4*)featw[w][lane])[1] = fb;
            }
            asm volatile("s_waitcnt lgkmcnt(0)" ::: "memory");
            // layer 1 (VALU, lane = channel), h1 tile -> LDS f16
            for (int e = 0; e < n_e; e++) {
                float4 fa = ((const float4*)featw[w][e])[0];    // broadcast b128
                float4 fb = ((const float4*)featw[w][e])[1];
                float a = b1c + fa.x * w1c[0] + fa.y * w1c[1] + fa.z * w1c[2] + fa.w * w1c[3]
                              + fb.x * w1c[4] + fb.y * w1c[5] + fb.z * w1c[6] + fb.w * w1c[7];
                float h1 = a > 0.f ? a : LK * a;
                h1s[w][e][lane] = (_Float16)h1;
            }
            asm volatile("s_waitcnt lgkmcnt(0)" ::: "memory");
            // layer 2 (MFMA): A[m=edge=lane&15][k=quad*8+j], K=64 via 2 chained
            f16x8 alo = *(const f16x8*)&h1s[w][col][quad * 8];
            f16x8 ahi = *(const f16x8*)&h1s[w][col][32 + quad * 8];
#pragma unroll
            for (int tt = 0; tt < 4; tt++) {
                f32x4 d2t = __builtin_amdgcn_mfma_f32_16x16x32_f16(alo, b2f[tt][0], zacc, 0, 0, 0);
                d2t = __builtin_amdgcn_mfma_f32_16x16x32_f16(ahi, b2f[tt][1], d2t, 0, 0, 0);
#pragma unroll
                for (int r = 0; r < 4; r++) {
                    int row = quad * 4 + r;        // D: row=edge, col=channel
                    float v = d2t[r] + b2t[tt];
                    v = v > 0.f ? v : LK * v;
                    bool val = row < n_e;           // stale rows masked out
                    vmx[tt] = fmaxf(vmx[tt], val ? v : -3.4e38f);
                    vmn[tt] = fminf(vmn[tt], val ? v : 3.4e38f);
                    float vs = val ? v : 0.f;
                    ssum4[tt] += vs;
                    ssq4[tt] += vs * vs;
                }
            }
        }
        // cross-quad (edge-dim) reduce; lanes 0-15 store each channel tile
#pragma unroll
        for (int tt = 0; tt < 4; tt++) {
            float mx = vmx[tt];
            mx = fmaxf(mx, __shfl_xor(mx, 16));
            mx = fmaxf(mx, __shfl_xor(mx, 32));
            float mn = vmn[tt];
            mn = fminf(mn, __shfl_xor(mn, 16));
            mn = fminf(mn, __shfl_xor(mn, 32));
            if (quad == 0) vsel[i * 64 + 16 * tt + col] = (gamt[tt] >= 0.f) ? mx : mn;
        }
    }

    // ---- BN stats: LDS channel accumulators then 16-way banked global atomics
#pragma unroll
    for (int tt = 0; tt < 4; tt++) {
        atomicAdd(&sums_s[16 * tt + col], ssum4[tt]);
        atomicAdd(&sumsq_s[16 * tt + col], ssq4[tt]);
    }
    __syncthreads();
    if (t < 64) {
        atomicAdd(&sums[((blockIdx.x & (NBANK - 1)) << 6) + t], sums_s[t]);
        atomicAdd(&sumsq[((blockIdx.x & (NBANK - 1)) << 6) + t], sumsq_s[t]);
    }
    if (t == 0) {
        int tot = 0;
#pragma unroll
        for (int q = 0; q < QPB; q++) tot += lcnt[q];
        atomicAdd(ecnt, tot);
    }
}

// ---------------- K2: BN affine + tuple passthrough, float4-vectorized
__global__ __launch_bounds__(256) void k2_fin(const float* __restrict__ wsf,
                                              const float* __restrict__ gamma,
                                              const float* __restrict__ beta,
                                              const float* __restrict__ pos,
                                              const int* __restrict__ braw,
                                              const float* __restrict__ rfl,
                                              const float* __restrict__ sf,
                                              float* __restrict__ out) {
    __shared__ float scl_s[64], shf_s[64];
    int tid = threadIdx.x;
    if (tid < 64) {
        float s = 0.f, s2 = 0.f;
#pragma unroll
        for (int b = 0; b < NBANK; b++) {
            s += wsf[F_SUMS + b * 64 + tid];
            s2 += wsf[F_SUMSQ + b * 64 + tid];
        }
        float cntf = (float)((const int*)wsf)[F_ECNT];
        float mean = s / cntf;
        float var = s2 / cntf - mean * mean;
        var = var > 0.f ? var : 0.f;
        float inv = 1.0f / sqrtf(var + EPSBN);
        float scl = gamma[tid] * inv;
        scl_s[tid] = scl;
        shf_s[tid] = beta[tid] - mean * scl;
    }
    __syncthreads();
    int o4 = blockIdx.x * 256 + tid;       // float4 index
    int o = o4 * 4;
    if (o >= O_TOT) return;
    float4 r;
    if (o < O_OUT) {
        float4 v = ((const float4*)(wsf + F_VSEL))[o4];
        int c = o & 63;
        r.x = scl_s[c + 0] * v.x + shf_s[c + 0];
        r.y = scl_s[c + 1] * v.y + shf_s[c + 1];
        r.z = scl_s[c + 2] * v.z + shf_s[c + 2];
        r.w = scl_s[c + 3] * v.w + shf_s[c + 3];
    } else if (o < O_POS) {
        r = ((const float4*)pos)[(o - O_OUT) >> 2];
    } else if (o < O_BAT) {
        int i = o - O_POS;
        int is64 = (braw[NP - 1] == 0) ? 1 : 0;
        r.x = (float)(is64 ? braw[2 * (i + 0)] : braw[i + 0]);
        r.y = (float)(is64 ? braw[2 * (i + 1)] : braw[i + 1]);
        r.z = (float)(is64 ? braw[2 * (i + 2)] : braw[i + 2]);
        r.w = (float)(is64 ? braw[2 * (i + 3)] : braw[i + 3]);
    } else if (o < O_RFL) {
        r = ((const float4*)rfl)[(o - O_BAT) >> 2];
    } else {
        r = ((const float4*)sf)[0];
    }
    ((float4*)out)[o4] = r;
}

extern "C" void kernel_launch(void* const* d_in, const int* in_sizes, int n_in,
                              void* d_out, int out_size, void* d_ws, size_t ws_size,
                              hipStream_t stream) {
    const float* xin  = (const float*)d_in[0];
    const float* pos  = (const float*)d_in[1];
    const float* rfl  = (const float*)d_in[2];
    const float* sf   = (const float*)d_in[3];
    const float* w1   = (const float*)d_in[4];
    const float* b1   = (const float*)d_in[5];
    const float* w2   = (const float*)d_in[6];
    const float* b2   = (const float*)d_in[7];
    const float* gam  = (const float*)d_in[8];
    const float* bet  = (const float*)d_in[9];
    const int*   brw  = (const int*)d_in[10];
    float* out = (float*)d_out;
    float* wsf = (float*)d_ws;

    k0_setup<<<1, 256, 0, stream>>>(brw, (int*)d_ws);
    k1_fused<<<NP / QPB, 256, 0, stream>>>(xin, pos, rfl, sf, w1, b1, w2, b2,
                                           gam, wsf);
    int n4 = (O_TOT + 3) / 4;
    k2_fin<<<(n4 + 255) / 256, 256, 0, stream>>>(wsf, gam, bet, pos, brw, rfl, sf, out);
}